// Round 1
// baseline (3107.759 us; speedup 1.0000x reference)
//
#include <hip/hip_runtime.h>
#include <cstdint>
#include <cstddef>

#define N_AREA 10000
#define N_FEAT 16
#define HID 64
#define BATCH 64
#define EPSL 1e-5f
#define SLOPE 0.01f

__device__ __forceinline__ float lrelu(float x) { return x >= 0.f ? x : SLOPE * x; }

__global__ __launch_bounds__(256) void k_zero(int* p, int n) {
    int i = blockIdx.x * 256 + threadIdx.x;
    if (i < n) p[i] = 0;
}

__global__ __launch_bounds__(256) void k_hist(const int* __restrict__ dst, int* __restrict__ counts, int E) {
    int e = blockIdx.x * 256 + threadIdx.x;
    if (e < E) atomicAdd(&counts[dst[e]], 1);
}

// Single-block scan: offsets (exclusive, incl. self-loop slot), dinv, self-loop CSR entry, cursor init.
__global__ __launch_bounds__(1024) void k_scan(const int* __restrict__ counts, int* __restrict__ offsets,
                                               int* __restrict__ cursor, float* __restrict__ dinv,
                                               int* __restrict__ csr_src, float* __restrict__ csr_norm) {
    const int PER = 10;
    int t = threadIdx.x;
    int base = t * PER;
    int local[PER];
    int sum = 0;
#pragma unroll
    for (int i = 0; i < PER; ++i) {
        int idx = base + i;
        int c = (idx < N_AREA) ? (counts[idx] + 1) : 0;  // +1 self loop
        local[i] = sum;
        sum += c;
    }
    __shared__ int part[1024];
    part[t] = sum;
    __syncthreads();
    for (int off = 1; off < 1024; off <<= 1) {
        int v = (t >= off) ? part[t - off] : 0;
        __syncthreads();
        part[t] += v;
        __syncthreads();
    }
    int excl = (t == 0) ? 0 : part[t - 1];
    if (t == 1023) offsets[N_AREA] = part[1023];
    for (int i = 0; i < PER; ++i) {
        int idx = base + i;
        if (idx < N_AREA) {
            int off = excl + local[i];
            offsets[idx] = off;
            float dv = rsqrtf((float)(counts[idx] + 1));
            dinv[idx] = dv;
            csr_src[off] = idx;          // self loop at slot 0
            csr_norm[off] = dv * dv;
            cursor[idx] = off + 1;
        }
    }
}

__global__ __launch_bounds__(256) void k_scatter(const int* __restrict__ ei, const float* __restrict__ dinv,
                                                 int* __restrict__ cursor, int* __restrict__ csr_src,
                                                 float* __restrict__ csr_norm, int E) {
    int e = blockIdx.x * 256 + threadIdx.x;
    if (e < E) {
        int s = ei[e], d = ei[E + e];
        int p = atomicAdd(&cursor[d], 1);
        csr_src[p] = s;
        csr_norm[p] = dinv[s] * dinv[d];
    }
}

// state [B][N][F] -> xT [N][B][F]
__global__ __launch_bounds__(256) void k_transpose(const float* __restrict__ s, float* __restrict__ d) {
    int tid = blockIdx.x * 256 + threadIdx.x;  // over N*B*F/4 = 2,560,000
    int n = tid >> 8;
    int rem = tid & 255;
    int b = rem >> 2, f4 = rem & 3;
    float4 v = *(const float4*)(s + (size_t)b * (N_AREA * N_FEAT) + n * N_FEAT + f4 * 4);
    *(float4*)(d + (size_t)n * (BATCH * N_FEAT) + b * N_FEAT + f4 * 4) = v;
}

// CSR gather: dst[n][:] = sum_e norm_e * src[csrc_e][:], row length NV*1024 floats
template <int NV>
__global__ __launch_bounds__(256) void k_gather(const float* __restrict__ src, float* __restrict__ dst,
                                                const int* __restrict__ offs, const int* __restrict__ csrc,
                                                const float* __restrict__ cnorm) {
    int n = blockIdx.x, t = threadIdx.x;
    int beg = offs[n], end = offs[n + 1];
    float4 acc[NV];
#pragma unroll
    for (int v = 0; v < NV; ++v) acc[v] = make_float4(0.f, 0.f, 0.f, 0.f);
    for (int e = beg; e < end; ++e) {
        int s = csrc[e];
        float w = cnorm[e];
        const float4* sp = (const float4*)(src + (size_t)s * (NV * 1024));
#pragma unroll
        for (int v = 0; v < NV; ++v) {
            float4 x = sp[v * 256 + t];
            acc[v].x += w * x.x;
            acc[v].y += w * x.y;
            acc[v].z += w * x.z;
            acc[v].w += w * x.w;
        }
    }
    float4* dp = (float4*)(dst + (size_t)n * (NV * 1024));
#pragma unroll
    for (int v = 0; v < NV; ++v) dp[v * 256 + t] = acc[v];
}

// h1 = leaky(LN(agg1 @ W1 + b1)); one wave per (n,b) row, lane = output channel
__global__ __launch_bounds__(256) void k_h1(const float* __restrict__ agg, const float* __restrict__ W1,
                                            const float* __restrict__ b1, const float* __restrict__ g1,
                                            const float* __restrict__ be1, float* __restrict__ h1) {
    int t = threadIdx.x;
    int lane = t & 63;
    int row = blockIdx.x * 4 + (t >> 6);  // < 640000
    const float* rp = agg + (size_t)row * N_FEAT;
    float acc = b1[lane];
#pragma unroll
    for (int f = 0; f < N_FEAT; ++f) acc += rp[f] * W1[f * HID + lane];
    float s = acc;
#pragma unroll
    for (int m = 1; m < 64; m <<= 1) s += __shfl_xor(s, m);
    float mu = s * (1.0f / 64.0f);
    float dv = acc - mu;
    float q = dv * dv;
#pragma unroll
    for (int m = 1; m < 64; m <<= 1) q += __shfl_xor(q, m);
    float rstd = rsqrtf(q * (1.0f / 64.0f) + EPSL);
    float y = dv * rstd * g1[lane] + be1[lane];
    y = lrelu(y);
    h1[(size_t)row * HID + lane] = y;
}

// 64x64 GEMM, 64 rows per block, 4x4 per thread.
// EPI 0: out = leaky(A@W+b) + resid
// EPI 1: out = leaky(LN(A@W+b; g,be)) + resid
// EPI 2: out[b_, n*64+c] = tanh(A@W+b)   (transposed store to [B][N][H])
template <int EPI>
__global__ __launch_bounds__(256) void k_gemm(const float* __restrict__ A, const float* __restrict__ W,
                                              const float* __restrict__ bias, const float* __restrict__ g,
                                              const float* __restrict__ be, const float* __restrict__ resid,
                                              float* __restrict__ out) {
    __shared__ float a_t[64][68];  // transposed A tile, padded for b128 alignment
    __shared__ float w_s[64][64];
    int t = threadIdx.x;
    int row0 = blockIdx.x * 64;
    {
        int k4 = t & 15, tl = t >> 4;
#pragma unroll
        for (int i = 0; i < 4; ++i) {
            int k = tl + i * 16;
            float4 wv = *(const float4*)(W + k * 64 + k4 * 4);
            *(float4*)(&w_s[k][k4 * 4]) = wv;
        }
#pragma unroll
        for (int i = 0; i < 4; ++i) {
            int r = tl + i * 16;
            float4 av = *(const float4*)(A + ((size_t)(row0 + r)) * 64 + k4 * 4);
            a_t[k4 * 4 + 0][r] = av.x;
            a_t[k4 * 4 + 1][r] = av.y;
            a_t[k4 * 4 + 2][r] = av.z;
            a_t[k4 * 4 + 3][r] = av.w;
        }
    }
    __syncthreads();
    int ty = t >> 4, tx = t & 15;
    int r0 = ty * 4, c0 = tx * 4;
    float acc[4][4] = {};
#pragma unroll
    for (int k = 0; k < 64; ++k) {
        float4 av = *(const float4*)(&a_t[k][r0]);
        float4 wv = *(const float4*)(&w_s[k][c0]);
        acc[0][0] += av.x * wv.x; acc[0][1] += av.x * wv.y; acc[0][2] += av.x * wv.z; acc[0][3] += av.x * wv.w;
        acc[1][0] += av.y * wv.x; acc[1][1] += av.y * wv.y; acc[1][2] += av.y * wv.z; acc[1][3] += av.y * wv.w;
        acc[2][0] += av.z * wv.x; acc[2][1] += av.z * wv.y; acc[2][2] += av.z * wv.z; acc[2][3] += av.z * wv.w;
        acc[3][0] += av.w * wv.x; acc[3][1] += av.w * wv.y; acc[3][2] += av.w * wv.z; acc[3][3] += av.w * wv.w;
    }
    float4 bv = *(const float4*)(bias + c0);
    float v[4][4];
#pragma unroll
    for (int i = 0; i < 4; ++i) {
        v[i][0] = acc[i][0] + bv.x;
        v[i][1] = acc[i][1] + bv.y;
        v[i][2] = acc[i][2] + bv.z;
        v[i][3] = acc[i][3] + bv.w;
    }
    if (EPI == 1) {
        float4 gv = *(const float4*)(g + c0);
        float4 bev = *(const float4*)(be + c0);
        float gg[4] = {gv.x, gv.y, gv.z, gv.w};
        float bb[4] = {bev.x, bev.y, bev.z, bev.w};
#pragma unroll
        for (int i = 0; i < 4; ++i) {
            float s = v[i][0] + v[i][1] + v[i][2] + v[i][3];
            float q = v[i][0] * v[i][0] + v[i][1] * v[i][1] + v[i][2] * v[i][2] + v[i][3] * v[i][3];
#pragma unroll
            for (int m = 1; m < 16; m <<= 1) {
                s += __shfl_xor(s, m);
                q += __shfl_xor(q, m);
            }
            float mu = s * (1.0f / 64.0f);
            float var = q * (1.0f / 64.0f) - mu * mu;
            float rstd = rsqrtf(var + EPSL);
#pragma unroll
            for (int j = 0; j < 4; ++j) v[i][j] = (v[i][j] - mu) * rstd * gg[j] + bb[j];
        }
    }
    if (EPI <= 1) {
#pragma unroll
        for (int i = 0; i < 4; ++i) {
            int R = row0 + r0 + i;
            float4 rv = *(const float4*)(resid + (size_t)R * 64 + c0);
            float4 o;
            o.x = lrelu(v[i][0]) + rv.x;
            o.y = lrelu(v[i][1]) + rv.y;
            o.z = lrelu(v[i][2]) + rv.z;
            o.w = lrelu(v[i][3]) + rv.w;
            *(float4*)(out + (size_t)R * 64 + c0) = o;
        }
    } else {
#pragma unroll
        for (int i = 0; i < 4; ++i) {
            int R = row0 + r0 + i;
            int nn = R >> 6, b_ = R & 63;  // R = n*BATCH + b
            float4 o;
            o.x = tanhf(v[i][0]);
            o.y = tanhf(v[i][1]);
            o.z = tanhf(v[i][2]);
            o.w = tanhf(v[i][3]);
            *(float4*)(out + (size_t)b_ * (N_AREA * HID) + (size_t)nn * HID + c0) = o;
        }
    }
}

extern "C" void kernel_launch(void* const* d_in, const int* in_sizes, int n_in,
                              void* d_out, int out_size, void* d_ws, size_t ws_size,
                              hipStream_t stream) {
    const float* state = (const float*)d_in[0];
    const int* ei = (const int*)d_in[1];
    const int E = in_sizes[1] / 2;
    const float* W1 = (const float*)d_in[5];
    const float* b1 = (const float*)d_in[6];
    const float* W2 = (const float*)d_in[7];
    const float* b2 = (const float*)d_in[8];
    const float* W3 = (const float*)d_in[9];
    const float* b3 = (const float*)d_in[10];
    const float* g1 = (const float*)d_in[11];
    const float* be1 = (const float*)d_in[12];
    const float* g3 = (const float*)d_in[13];
    const float* be3 = (const float*)d_in[14];
    const float* Wf = (const float*)d_in[15];
    const float* bf = (const float*)d_in[16];
    float* out = (float*)d_out;

    uint8_t* base = (uint8_t*)d_ws;
    size_t off = 0;
    auto carve = [&](size_t bytes) {
        void* p = base + off;
        off = (off + bytes + 255) & ~(size_t)255;
        return p;
    };
    float* dinv = (float*)carve(N_AREA * 4);
    int* counts = (int*)carve(N_AREA * 4);
    int* offsets = (int*)carve((N_AREA + 1) * 4);
    int* cursor = (int*)carve(N_AREA * 4);
    int* csr_src = (int*)carve((size_t)(E + N_AREA) * 4);
    float* csr_norm = (float*)carve((size_t)(E + N_AREA) * 4);
    float* xT = (float*)carve((size_t)N_AREA * BATCH * N_FEAT * 4);
    float* agg1 = (float*)carve((size_t)N_AREA * BATCH * N_FEAT * 4);
    float* h1 = (float*)carve((size_t)N_AREA * BATCH * HID * 4);
    float* h2 = (float*)carve((size_t)N_AREA * BATCH * HID * 4);

    // 1. degree + CSR build
    k_zero<<<(N_AREA + 255) / 256, 256, 0, stream>>>(counts, N_AREA);
    k_hist<<<(E + 255) / 256, 256, 0, stream>>>(ei + E, counts, E);
    k_scan<<<1, 1024, 0, stream>>>(counts, offsets, cursor, dinv, csr_src, csr_norm);
    k_scatter<<<(E + 255) / 256, 256, 0, stream>>>(ei, dinv, cursor, csr_src, csr_norm, E);

    // 2. x -> [N][B][F]; agg1 = A @ x
    k_transpose<<<(N_AREA * BATCH * N_FEAT / 4) / 256, 256, 0, stream>>>(state, xT);
    k_gather<1><<<N_AREA, 256, 0, stream>>>(xT, agg1, offsets, csr_src, csr_norm);

    // 3. h1 = leaky(LN(agg1 @ W1 + b1))
    k_h1<<<(N_AREA * BATCH) / 4, 256, 0, stream>>>(agg1, W1, b1, g1, be1, h1);

    // 4. conv2: agg2 = A @ h1 (into d_out); h2 = leaky(agg2 @ W2 + b2) + h1
    k_gather<4><<<N_AREA, 256, 0, stream>>>(h1, out, offsets, csr_src, csr_norm);
    k_gemm<0><<<(N_AREA * BATCH) / 64, 256, 0, stream>>>(out, W2, b2, nullptr, nullptr, h1, h2);

    // 5. conv3: agg3 = A @ h2 (into d_out); h3 = leaky(LN(agg3 @ W3 + b3)) + h1 (into h2 buf)
    k_gather<4><<<N_AREA, 256, 0, stream>>>(h2, out, offsets, csr_src, csr_norm);
    k_gemm<1><<<(N_AREA * BATCH) / 64, 256, 0, stream>>>(out, W3, b3, g3, be3, h1, h2);

    // 6. out = tanh(h3 @ Wf + bf), transposed to [B][N*H]
    k_gemm<2><<<(N_AREA * BATCH) / 64, 256, 0, stream>>>(h2, Wf, bf, nullptr, nullptr, nullptr, out);
}

// Round 2
// 2764.724 us; speedup vs baseline: 1.1241x; 1.1241x over previous
//
#include <hip/hip_runtime.h>
#include <cstdint>
#include <cstddef>

#define N_AREA 10000
#define N_FEAT 16
#define HID 64
#define BATCH 64
#define EPSL 1e-5f
#define SLOPE 0.01f
#define NCHUNK 157  // ceil(10000/64)

__device__ __forceinline__ float lrelu(float x) { return x >= 0.f ? x : SLOPE * x; }
__device__ __forceinline__ float tanh_fast(float x) {
    float t = __expf(2.0f * x);  // v_exp_f32 path
    return 1.0f - 2.0f / (t + 1.0f);
}

__global__ __launch_bounds__(256) void k_zero(int* p, int n) {
    int i = blockIdx.x * 256 + threadIdx.x;
    if (i < n) p[i] = 0;
}

__global__ __launch_bounds__(256) void k_hist(const int* __restrict__ dst, int* __restrict__ counts, int E) {
    int e = blockIdx.x * 256 + threadIdx.x;
    if (e < E) atomicAdd(&counts[dst[e]], 1);
}

// offsets (exclusive, +1 self-loop slot), dinv, self-loop entry, cursor init.
__global__ __launch_bounds__(1024) void k_scan(const int* __restrict__ counts, int* __restrict__ offsets,
                                               int* __restrict__ cursor, float* __restrict__ dinv,
                                               int2* __restrict__ ew) {
    const int PER = 10;
    int t = threadIdx.x;
    int base = t * PER;
    int local[PER];
    int sum = 0;
#pragma unroll
    for (int i = 0; i < PER; ++i) {
        int idx = base + i;
        int c = (idx < N_AREA) ? (counts[idx] + 1) : 0;
        local[i] = sum;
        sum += c;
    }
    __shared__ int part[1024];
    part[t] = sum;
    __syncthreads();
    for (int off = 1; off < 1024; off <<= 1) {
        int v = (t >= off) ? part[t - off] : 0;
        __syncthreads();
        part[t] += v;
        __syncthreads();
    }
    int excl = (t == 0) ? 0 : part[t - 1];
    if (t == 1023) offsets[N_AREA] = part[1023];
    for (int i = 0; i < PER; ++i) {
        int idx = base + i;
        if (idx < N_AREA) {
            int off = excl + local[i];
            offsets[idx] = off;
            float dv = rsqrtf((float)(counts[idx] + 1));
            dinv[idx] = dv;
            ew[off] = make_int2(idx, __float_as_int(dv * dv));  // self loop
            cursor[idx] = off + 1;
        }
    }
}

__global__ __launch_bounds__(256) void k_scatter(const int* __restrict__ ei, const float* __restrict__ dinv,
                                                 int* __restrict__ cursor, int2* __restrict__ ew, int E) {
    int e = blockIdx.x * 256 + threadIdx.x;
    if (e < E) {
        int s = ei[e], d = ei[E + e];
        int p = atomicAdd(&cursor[d], 1);
        ew[p] = make_int2(s, __float_as_int(dinv[s] * dinv[d]));
    }
}

// conv1 fused: gather(state rows of 16) -> @W1+b1 -> LN -> leaky -> h1 [B][N][64]
__global__ __launch_bounds__(256, 4) void k_conv1(const float* __restrict__ state, const float* __restrict__ W1,
                                                  const float* __restrict__ b1, const float* __restrict__ g1,
                                                  const float* __restrict__ be1, float* __restrict__ h1,
                                                  const int* __restrict__ offs, const int2* __restrict__ ew) {
    __shared__ float xs[64][20];  // padded: node stride 20 floats keeps b128 aligned + banks spread
    __shared__ float ws[16][64];
    int blk = blockIdx.x;
    int xc = blk & 7, ii = blk >> 3;  // XCD group: batch b on XCD b%8
    int b = xc + 8 * (ii / NCHUNK);
    int c = ii % NCHUNK;
    int n0 = c * 64;
    int t = threadIdx.x;
    *(float4*)&ws[t >> 4][(t & 15) * 4] = *(const float4*)(W1 + (t >> 4) * HID + (t & 15) * 4);
    int ln = t >> 2, q = t & 3;
    int n = n0 + ln;
    const float* sb = state + (size_t)b * (N_AREA * N_FEAT);
    float4 acc = make_float4(0.f, 0.f, 0.f, 0.f);
    if (n < N_AREA) {
        int beg = offs[n], end = offs[n + 1];
        for (int e = beg; e < end; ++e) {
            int2 sw = ew[e];
            float w = __int_as_float(sw.y);
            float4 v = *(const float4*)(sb + (size_t)sw.x * N_FEAT + q * 4);
            acc.x += w * v.x; acc.y += w * v.y; acc.z += w * v.z; acc.w += w * v.w;
        }
    }
    *(float4*)&xs[ln][q * 4] = acc;
    __syncthreads();
    int wave = t >> 6, lane = t & 63;
    float bias = b1[lane], gg = g1[lane], bb = be1[lane];
    for (int j = 0; j < 16; ++j) {
        int lnn = wave * 16 + j;
        float a = bias;
#pragma unroll
        for (int f = 0; f < N_FEAT; ++f) a += xs[lnn][f] * ws[f][lane];
        float s = a;
#pragma unroll
        for (int m = 1; m < 64; m <<= 1) s += __shfl_xor(s, m);
        float mu = s * (1.0f / 64.0f);
        float dv = a - mu;
        float qv = dv * dv;
#pragma unroll
        for (int m = 1; m < 64; m <<= 1) qv += __shfl_xor(qv, m);
        float rstd = rsqrtf(qv * (1.0f / 64.0f) + EPSL);
        float y = lrelu(dv * rstd * gg + bb);
        int nn = n0 + lnn;
        if (nn < N_AREA) h1[(size_t)b * (N_AREA * HID) + (size_t)nn * HID + lane] = y;
    }
}

// Fused conv: gather(src rows of 64, L2-resident per-batch slice) into LDS -> 64x64 GEMM -> epilogue
// EPI 0: out = leaky(.+b) + resid    EPI 1: out = leaky(LN(.+b)) + resid
template <int EPI>
__global__ __launch_bounds__(256, 4) void k_conv(const float* __restrict__ src, const float* __restrict__ W,
                                                 const float* __restrict__ bias, const float* __restrict__ g,
                                                 const float* __restrict__ be, const float* __restrict__ resid,
                                                 float* __restrict__ out, const int* __restrict__ offs,
                                                 const int2* __restrict__ ew) {
    __shared__ float a_t[64][68];  // [feat][node]
    __shared__ float w_s[64][64];
    int blk = blockIdx.x;
    int xc = blk & 7, ii = blk >> 3;
    int b = xc + 8 * (ii / NCHUNK);
    int c = ii % NCHUNK;
    int n0 = c * 64;
    int t = threadIdx.x;
    {
        int k4 = t & 15, tl = t >> 4;
#pragma unroll
        for (int j = 0; j < 4; ++j) {
            int k = tl + j * 16;
            *(float4*)&w_s[k][k4 * 4] = *(const float4*)(W + k * HID + k4 * 4);
        }
    }
    int wave = t >> 6, lane = t & 63;
    const float* sb = src + (size_t)b * (N_AREA * HID);
    for (int j = 0; j < 16; ++j) {
        int ln = wave * 16 + j;
        int n = n0 + ln;
        float acc = 0.f;
        if (n < N_AREA) {
            int beg = offs[n], end = offs[n + 1];
            int e = beg;
            for (; e + 3 < end; e += 4) {
                int2 e0 = ew[e], e1 = ew[e + 1], e2 = ew[e + 2], e3 = ew[e + 3];
                float v0 = sb[(size_t)e0.x * HID + lane];
                float v1 = sb[(size_t)e1.x * HID + lane];
                float v2 = sb[(size_t)e2.x * HID + lane];
                float v3 = sb[(size_t)e3.x * HID + lane];
                acc += __int_as_float(e0.y) * v0;
                acc += __int_as_float(e1.y) * v1;
                acc += __int_as_float(e2.y) * v2;
                acc += __int_as_float(e3.y) * v3;
            }
            for (; e < end; ++e) {
                int2 e0 = ew[e];
                acc += __int_as_float(e0.y) * sb[(size_t)e0.x * HID + lane];
            }
        }
        a_t[lane][ln] = acc;
    }
    __syncthreads();
    int ty = t >> 4, tx = t & 15;
    int r0 = ty * 4, c0 = tx * 4;
    float am[4][4] = {};
#pragma unroll 4
    for (int k = 0; k < 64; ++k) {
        float4 av = *(const float4*)&a_t[k][r0];
        float4 wv = *(const float4*)&w_s[k][c0];
        am[0][0] += av.x * wv.x; am[0][1] += av.x * wv.y; am[0][2] += av.x * wv.z; am[0][3] += av.x * wv.w;
        am[1][0] += av.y * wv.x; am[1][1] += av.y * wv.y; am[1][2] += av.y * wv.z; am[1][3] += av.y * wv.w;
        am[2][0] += av.z * wv.x; am[2][1] += av.z * wv.y; am[2][2] += av.z * wv.z; am[2][3] += av.z * wv.w;
        am[3][0] += av.w * wv.x; am[3][1] += av.w * wv.y; am[3][2] += av.w * wv.z; am[3][3] += av.w * wv.w;
    }
    float4 bv = *(const float4*)(bias + c0);
    float v[4][4];
#pragma unroll
    for (int i = 0; i < 4; ++i) {
        v[i][0] = am[i][0] + bv.x;
        v[i][1] = am[i][1] + bv.y;
        v[i][2] = am[i][2] + bv.z;
        v[i][3] = am[i][3] + bv.w;
    }
    if (EPI == 1) {
        float4 gv = *(const float4*)(g + c0);
        float4 bev = *(const float4*)(be + c0);
        float gg[4] = {gv.x, gv.y, gv.z, gv.w};
        float bb[4] = {bev.x, bev.y, bev.z, bev.w};
#pragma unroll
        for (int i = 0; i < 4; ++i) {
            float s = v[i][0] + v[i][1] + v[i][2] + v[i][3];
            float qv = v[i][0] * v[i][0] + v[i][1] * v[i][1] + v[i][2] * v[i][2] + v[i][3] * v[i][3];
#pragma unroll
            for (int m = 1; m < 16; m <<= 1) {
                s += __shfl_xor(s, m);
                qv += __shfl_xor(qv, m);
            }
            float mu = s * (1.0f / 64.0f);
            float var = qv * (1.0f / 64.0f) - mu * mu;
            float rstd = rsqrtf(var + EPSL);
#pragma unroll
            for (int j = 0; j < 4; ++j) v[i][j] = (v[i][j] - mu) * rstd * gg[j] + bb[j];
        }
    }
    const float* rb = resid + (size_t)b * (N_AREA * HID);
    float* ob = out + (size_t)b * (N_AREA * HID);
#pragma unroll
    for (int i = 0; i < 4; ++i) {
        int n = n0 + r0 + i;
        if (n < N_AREA) {
            float4 rv = *(const float4*)(rb + (size_t)n * HID + c0);
            float4 o;
            o.x = lrelu(v[i][0]) + rv.x;
            o.y = lrelu(v[i][1]) + rv.y;
            o.z = lrelu(v[i][2]) + rv.z;
            o.w = lrelu(v[i][3]) + rv.w;
            *(float4*)(ob + (size_t)n * HID + c0) = o;
        }
    }
}

// Final: out = tanh(A @ Wf + bf), in-place on d_out rows (each block touches only its own rows)
__global__ __launch_bounds__(256, 4) void k_gemmF(const float* __restrict__ A, const float* __restrict__ W,
                                                  const float* __restrict__ bias, float* __restrict__ out) {
    __shared__ float a_t[64][68];
    __shared__ float w_s[64][64];
    int blk = blockIdx.x;
    int xc = blk & 7, ii = blk >> 3;
    int b = xc + 8 * (ii / NCHUNK);
    int c = ii % NCHUNK;
    int n0 = c * 64;
    int t = threadIdx.x;
    {
        int k4 = t & 15, tl = t >> 4;
#pragma unroll
        for (int j = 0; j < 4; ++j) {
            int k = tl + j * 16;
            *(float4*)&w_s[k][k4 * 4] = *(const float4*)(W + k * HID + k4 * 4);
        }
        const float* ab = A + (size_t)b * (N_AREA * HID);
#pragma unroll
        for (int j = 0; j < 4; ++j) {
            int r = tl + j * 16;
            int n = n0 + r;
            int nc = n < N_AREA ? n : (N_AREA - 1);
            float4 av = *(const float4*)(ab + (size_t)nc * HID + k4 * 4);
            a_t[k4 * 4 + 0][r] = av.x;
            a_t[k4 * 4 + 1][r] = av.y;
            a_t[k4 * 4 + 2][r] = av.z;
            a_t[k4 * 4 + 3][r] = av.w;
        }
    }
    __syncthreads();
    int ty = t >> 4, tx = t & 15;
    int r0 = ty * 4, c0 = tx * 4;
    float am[4][4] = {};
#pragma unroll 4
    for (int k = 0; k < 64; ++k) {
        float4 av = *(const float4*)&a_t[k][r0];
        float4 wv = *(const float4*)&w_s[k][c0];
        am[0][0] += av.x * wv.x; am[0][1] += av.x * wv.y; am[0][2] += av.x * wv.z; am[0][3] += av.x * wv.w;
        am[1][0] += av.y * wv.x; am[1][1] += av.y * wv.y; am[1][2] += av.y * wv.z; am[1][3] += av.y * wv.w;
        am[2][0] += av.z * wv.x; am[2][1] += av.z * wv.y; am[2][2] += av.z * wv.z; am[2][3] += av.z * wv.w;
        am[3][0] += av.w * wv.x; am[3][1] += av.w * wv.y; am[3][2] += av.w * wv.z; am[3][3] += av.w * wv.w;
    }
    float4 bv = *(const float4*)(bias + c0);
    float* ob = out + (size_t)b * (N_AREA * HID);
#pragma unroll
    for (int i = 0; i < 4; ++i) {
        int n = n0 + r0 + i;
        if (n < N_AREA) {
            float4 o;
            o.x = tanh_fast(am[i][0] + bv.x);
            o.y = tanh_fast(am[i][1] + bv.y);
            o.z = tanh_fast(am[i][2] + bv.z);
            o.w = tanh_fast(am[i][3] + bv.w);
            *(float4*)(ob + (size_t)n * HID + c0) = o;
        }
    }
}

extern "C" void kernel_launch(void* const* d_in, const int* in_sizes, int n_in,
                              void* d_out, int out_size, void* d_ws, size_t ws_size,
                              hipStream_t stream) {
    const float* state = (const float*)d_in[0];
    const int* ei = (const int*)d_in[1];
    const int E = in_sizes[1] / 2;
    const float* W1 = (const float*)d_in[5];
    const float* b1 = (const float*)d_in[6];
    const float* W2 = (const float*)d_in[7];
    const float* b2 = (const float*)d_in[8];
    const float* W3 = (const float*)d_in[9];
    const float* b3 = (const float*)d_in[10];
    const float* g1 = (const float*)d_in[11];
    const float* be1 = (const float*)d_in[12];
    const float* g3 = (const float*)d_in[13];
    const float* be3 = (const float*)d_in[14];
    const float* Wf = (const float*)d_in[15];
    const float* bf = (const float*)d_in[16];
    float* out = (float*)d_out;

    uint8_t* base = (uint8_t*)d_ws;
    size_t off = 0;
    auto carve = [&](size_t bytes) {
        void* p = base + off;
        off = (off + bytes + 255) & ~(size_t)255;
        return p;
    };
    float* dinv = (float*)carve(N_AREA * 4);
    int* counts = (int*)carve(N_AREA * 4);
    int* offsets = (int*)carve((N_AREA + 1) * 4);
    int* cursor = (int*)carve(N_AREA * 4);
    int2* ew = (int2*)carve((size_t)(E + N_AREA) * 8);
    float* h1 = (float*)carve((size_t)BATCH * N_AREA * HID * 4);
    float* h2 = (float*)carve((size_t)BATCH * N_AREA * HID * 4);

    const int GRID = 8 * NCHUNK * (BATCH / 8);  // 10048

    k_zero<<<(N_AREA + 255) / 256, 256, 0, stream>>>(counts, N_AREA);
    k_hist<<<(E + 255) / 256, 256, 0, stream>>>(ei + E, counts, E);
    k_scan<<<1, 1024, 0, stream>>>(counts, offsets, cursor, dinv, ew);
    k_scatter<<<(E + 255) / 256, 256, 0, stream>>>(ei, dinv, cursor, ew, E);

    k_conv1<<<GRID, 256, 0, stream>>>(state, W1, b1, g1, be1, h1, offsets, ew);
    k_conv<0><<<GRID, 256, 0, stream>>>(h1, W2, b2, nullptr, nullptr, h1, h2, offsets, ew);
    k_conv<1><<<GRID, 256, 0, stream>>>(h2, W3, b3, g3, be3, h1, out, offsets, ew);
    k_gemmF<<<GRID, 256, 0, stream>>>(out, Wf, bf, out);
}